// Round 19
// baseline (101.161 us; speedup 1.0000x reference)
//
#include <hip/hip_runtime.h>
#include <hip/hip_bf16.h>

#define N_ROWS 8192
#define DIM 256
#define R_BLK 128          // row-slots per block (4 waves x 32)
#define C_CHUNK 256        // cols per block
#define TILE_C 32          // cols per inner tile
#define N_CHUNKS 32
#define N_ITERS (C_CHUNK / TILE_C)   // 8

typedef __attribute__((ext_vector_type(4))) float f32x4;
typedef __attribute__((ext_vector_type(8))) short bf16x8;

__device__ __forceinline__ ushort f2bf(float v) {
    __hip_bfloat16 h = __float2bfloat16(v);
    return *reinterpret_cast<ushort*>(&h);
}

// ---------------- Kernel A: normalize rows -> bf16 + per-block compaction ----------------
// 256 blocks x 32 contiguous rows. One atomicAdd per block (spread out, not serialized).
// ridx slot order non-deterministic; per-row results are slot-invariant -> deterministic output.
__global__ __launch_bounds__(256) void prep_kernel(const float* __restrict__ feat,
                                                   const float* __restrict__ ious,
                                                   const int* __restrict__ labels,
                                                   ushort* __restrict__ fhi,
                                                   int* __restrict__ ridx,
                                                   int* __restrict__ nact) {
    const int wid  = threadIdx.x >> 6;
    const int lane = threadIdx.x & 63;
#pragma unroll
    for (int r8 = 0; r8 < 8; ++r8) {
        const int row = blockIdx.x * 32 + r8 * 4 + wid;
        const float4 x = reinterpret_cast<const float4*>(feat + (size_t)row * DIM)[lane];
        float ss = x.x * x.x + x.y * x.y + x.z * x.z + x.w * x.w;
#pragma unroll
        for (int off = 32; off; off >>= 1) ss += __shfl_xor(ss, off);
        const float inv = 1.0f / fmaxf(sqrtf(ss), 1e-12f);
        ushort4 h;
        h.x = f2bf(x.x * inv); h.y = f2bf(x.y * inv);
        h.z = f2bf(x.z * inv); h.w = f2bf(x.w * inv);
        reinterpret_cast<ushort4*>(fhi + (size_t)row * DIM)[lane] = h;
    }
    if (threadIdx.x < 64) {            // wave 0 compacts this block's 32 rows
        const int row = min(blockIdx.x * 32 + lane, N_ROWS - 1);
        const bool act = (lane < 32) && (labels[row] >= 0) && (ious[row] > 0.5f);
        const unsigned long long mb = __ballot(act);
        const int off = __popcll(mb & ((1ull << lane) - 1ull));
        const int tot = __popcll(mb);
        int base = 0;
        if (lane == 0 && tot) base = atomicAdd(nact, tot);
        base = __shfl(base, 0);
        if (act) ridx[base + off] = row;
    }
}

// ---------------- Kernel B: fused sim + mask + fixed-max softmax partials ----------------
// NO LDS, NO BARRIERS: B fragments read directly from global (L2-resident, fragment-order
// addressing: loop-invariant per-lane base + t*64 immediate offsets). Waves run free;
// compiler software-pipelines the independent register loads across MFMA.
// grid = 2048: chunk = bid&31 (256 cols), rowblk = bid>>5 (128 active-row slots).
// launch_bounds (256,3): VGPR cap ~168; (256,4) spills A-fragments (round-14 post-mortem).
__global__ __launch_bounds__(256, 3) void main_kernel(const ushort* __restrict__ fhi,
                                                      const float* __restrict__ ious,
                                                      const int* __restrict__ labels,
                                                      const int* __restrict__ ridx,
                                                      const int* __restrict__ nact,
                                                      float* __restrict__ ps_part,
                                                      float* __restrict__ as_part) {
    const int nactive = nact[0];
    const int bid   = blockIdx.x;
    const int rbase = (bid >> 5) * R_BLK;
    if (rbase >= nactive) return;      // uniform early-exit

    const int chunk = bid & (N_CHUNKS - 1);
    const int c0    = chunk * C_CHUNK;

    const int tid  = threadIdx.x;
    const int lane = tid & 63;
    const int w    = tid >> 6;          // 0..3
    const int lrow = lane & 15;
    const int kg   = lane >> 4;         // 0..3
    const int s0   = rbase + w * 32;    // this wave's first row-slot

    // A fragments: two 16-row tiles (gathered via ridx) x 256 k in registers (64 VGPR)
    bf16x8 av0[8], av1[8];
    {
        const int rowA0 = ridx[min(s0 + lrow,      nactive - 1)];
        const int rowA1 = ridx[min(s0 + 16 + lrow, nactive - 1)];
        const ushort* pa0 = fhi + (size_t)rowA0 * DIM + kg * 8;
        const ushort* pa1 = fhi + (size_t)rowA1 * DIM + kg * 8;
#pragma unroll
        for (int t = 0; t < 8; ++t) {
            av0[t] = *reinterpret_cast<const bf16x8*>(pa0 + t * 32);
            av1[t] = *reinterpret_cast<const bf16x8*>(pa1 + t * 32);
        }
    }

    // row metadata for the 8 row-slots this lane covers (C/D: col=lane&15, row=kg*4+reg)
    int rowm[8]; int labi[8]; float ioui[8]; int livem = 0;
#pragma unroll
    for (int m = 0; m < 8; ++m) {
        const int rt = m >> 2, r = m & 3;
        const int slot = s0 + rt * 16 + kg * 4 + r;
        const bool lv = slot < nactive;
        livem |= lv ? (1 << m) : 0;
        const int gi = ridx[min(slot, nactive - 1)];
        rowm[m] = gi;
        labi[m] = lv ? labels[gi] : -2;   // -2: matches no column label
        ioui[m] = ious[gi];
    }

    float ps[8], as_[8];
#pragma unroll
    for (int m = 0; m < 8; ++m) { ps[m] = 0.f; as_[m] = 0.f; }

    // per-lane B fragment base pointers (fragment-order direct-global reads)
    const char* fhib = (const char*)fhi;
    const char* b0p = fhib + (((size_t)(c0 + lrow)) << 9)      + kg * 16;
    const char* b1p = fhib + (((size_t)(c0 + 16 + lrow)) << 9) + kg * 16;

    const float C1 = 14.42695041f;   // 10*log2(e): e = exp2(acc*C1 - C1) == exp(sim-10)
    for (int it = 0; it < N_ITERS; ++it) {
        const int jcl = it * TILE_C;
        const int colg0 = c0 + jcl + lrow;
        const int colg1 = colg0 + 16;
        const int labj0 = labels[colg0];
        const int labj1 = labels[colg1];
        const float iouj0 = ious[colg0];
        const float iouj1 = ious[colg1];

        f32x4 acc00 = {0.f,0.f,0.f,0.f}, acc01 = {0.f,0.f,0.f,0.f};
        f32x4 acc10 = {0.f,0.f,0.f,0.f}, acc11 = {0.f,0.f,0.f,0.f};
#pragma unroll
        for (int t = 0; t < 8; ++t) {
            bf16x8 b0 = *reinterpret_cast<const bf16x8*>(b0p + t * 64);
            bf16x8 b1 = *reinterpret_cast<const bf16x8*>(b1p + t * 64);
            acc00 = __builtin_amdgcn_mfma_f32_16x16x32_bf16(av0[t], b0, acc00, 0, 0, 0);
            acc01 = __builtin_amdgcn_mfma_f32_16x16x32_bf16(av0[t], b1, acc01, 0, 0, 0);
            acc10 = __builtin_amdgcn_mfma_f32_16x16x32_bf16(av1[t], b0, acc10, 0, 0, 0);
            acc11 = __builtin_amdgcn_mfma_f32_16x16x32_bf16(av1[t], b1, acc11, 0, 0, 0);
        }
        b0p += TILE_C * 512;   // next 32-column tile
        b1p += TILE_C * 512;

        // epilogue (active rows: hi_i true, ng_i false, fg_i true):
        //   pos = same && iouj>0.5 && |d|<0.2 && fgj && i!=j
        //   allm = (fgj && i!=j) && (ioum || !same)
#pragma unroll
        for (int rt = 0; rt < 2; ++rt) {
#pragma unroll
            for (int half = 0; half < 2; ++half) {
                const int colg = half ? colg1 : colg0;
                const int labj = half ? labj1 : labj0;
                const float iouj = half ? iouj1 : iouj0;
                const f32x4 acc = rt ? (half ? acc11 : acc10) : (half ? acc01 : acc00);
                const bool fgj = labj >= 0;
                const bool hij = iouj > 0.5f;
#pragma unroll
                for (int r = 0; r < 4; ++r) {
                    const int m  = rt * 4 + r;
                    const bool same = (labi[m] == labj);
                    const bool ioum = hij && (fabsf(iouj - ioui[m]) < 0.2f);
                    const bool pf   = fgj && (rowm[m] != colg);
                    const bool pos  = same && ioum && pf;
                    const bool allm = pf && (ioum || !same);
                    const float e = allm ? exp2f(fmaf(acc[r], C1, -C1)) : 0.0f;
                    as_[m] += e;
                    ps[m]  += pos ? e : 0.0f;
                }
            }
        }
    }

    // reduce over the 16 lanes (lrow) holding col-slices of the same rows
#pragma unroll
    for (int off = 1; off < 16; off <<= 1) {
#pragma unroll
        for (int m = 0; m < 8; ++m) {
            ps[m]  += __shfl_xor(ps[m], off);
            as_[m] += __shfl_xor(as_[m], off);
        }
    }

    if (lrow == 0) {
#pragma unroll
        for (int m = 0; m < 8; ++m) {
            if ((livem >> m) & 1) {
                const int idx = chunk * N_ROWS + rowm[m];
                ps_part[idx] = ps[m];
                as_part[idx] = as_[m];
            }
        }
    }
}

// ---------------- Kernel C: combine chunk partials -> per-row loss -> mean (fused) ----------------
__global__ __launch_bounds__(256) void combine_kernel(const float* __restrict__ ps_part,
                                                      const float* __restrict__ as_part,
                                                      const float* __restrict__ ious,
                                                      const int* __restrict__ labels,
                                                      float* __restrict__ partT,
                                                      float* __restrict__ partC,
                                                      int* __restrict__ done,
                                                      float* __restrict__ out) {
    const int tid = threadIdx.x;
    const int row = blockIdx.x * 256 + tid;
    const bool act = (labels[row] >= 0) && (ious[row] > 0.5f);
    float loss = 0.f, vld = 0.f;
    if (act) {
        float P = 0.f, A = 0.f;
#pragma unroll
        for (int c = 0; c < N_CHUNKS; ++c) {
            P += ps_part[c * N_ROWS + row];
            A += as_part[c * N_ROWS + row];
        }
        const float psc = fminf(fmaxf(P, 1e-6f), 1e6f);
        const float asc = fminf(fmaxf(A, 1e-6f), 1e6f);
        const bool valid = (P > 0.0f) && (A > P);
        loss = valid ? fminf(__logf(asc) - __logf(psc), 10.0f) : 0.0f;
        vld  = valid ? 1.0f : 0.0f;
    }
    float tl = loss, tc = vld;
#pragma unroll
    for (int off = 32; off; off >>= 1) { tl += __shfl_down(tl, off); tc += __shfl_down(tc, off); }
    __shared__ float sl[4], sc[4];
    const int wid = tid >> 6;
    if ((tid & 63) == 0) { sl[wid] = tl; sc[wid] = tc; }
    __syncthreads();
    if (tid == 0) {
        partT[blockIdx.x] = sl[0] + sl[1] + sl[2] + sl[3];
        partC[blockIdx.x] = sc[0] + sc[1] + sc[2] + sc[3];
        __threadfence();
        const int prev = atomicAdd(done, 1);
        if (prev == (int)gridDim.x - 1) {      // last block finalizes (fixed order: deterministic)
            __threadfence();
            float T = 0.f, C = 0.f;
#pragma unroll
            for (int b = 0; b < N_ROWS / 256; ++b) { T += partT[b]; C += partC[b]; }
            out[0] = (C > 0.f) ? (T / C) : 0.0f;
        }
    }
}

extern "C" void kernel_launch(void* const* d_in, const int* in_sizes, int n_in,
                              void* d_out, int out_size, void* d_ws, size_t ws_size,
                              hipStream_t stream) {
    const float* feat   = (const float*)d_in[0];
    const float* ious   = (const float*)d_in[1];
    const int*   labels = (const int*)d_in[2];
    float* out = (float*)d_out;

    ushort* fhi = (ushort*)d_ws;                                     // 4 MB
    float*  ps_part = (float*)(fhi + (size_t)N_ROWS * DIM);          // 1 MB
    float*  as_part = ps_part + (size_t)N_CHUNKS * N_ROWS;           // 1 MB
    int*    ridx = (int*)(as_part + (size_t)N_CHUNKS * N_ROWS);      // 32 KB
    int*    ctrs = ridx + N_ROWS;                                    // nact, done
    float*  partT = (float*)(ctrs + 2);                              // 32 floats
    float*  partC = partT + (N_ROWS / 256);                          // 32 floats

    hipMemsetAsync(ctrs, 0, 2 * sizeof(int), stream);
    prep_kernel<<<256, 256, 0, stream>>>(feat, ious, labels, fhi, ridx, ctrs);
    main_kernel<<<(N_ROWS / R_BLK) * N_CHUNKS, 256, 0, stream>>>(fhi, ious, labels,
                                                                 ridx, ctrs, ps_part, as_part);
    combine_kernel<<<N_ROWS / 256, 256, 0, stream>>>(ps_part, as_part, ious, labels,
                                                     partT, partC, ctrs + 1, out);
}

// Round 20
// 60.413 us; speedup vs baseline: 1.6745x; 1.6745x over previous
//
#include <hip/hip_runtime.h>
#include <hip/hip_bf16.h>

#define N_ROWS 8192
#define DIM 256
#define R_BLK 128          // row-slots per block (4 waves x 32)
#define C_CHUNK 512        // cols per block
#define TILE_C 64          // cols per LDS tile (2 barriers per 64 cols)
#define N_CHUNKS 16
#define N_ITERS (C_CHUNK / TILE_C)   // 8

typedef __attribute__((ext_vector_type(4))) float f32x4;
typedef __attribute__((ext_vector_type(8))) short bf16x8;

__device__ __forceinline__ void gload_lds16(const void* g, void* l) {
    using gv = const __attribute__((address_space(1))) void*;
    using sv = __attribute__((address_space(3))) void*;
    __builtin_amdgcn_global_load_lds((gv)g, (sv)l, 16, 0, 0);
}

__device__ __forceinline__ ushort f2bf(float v) {
    __hip_bfloat16 h = __float2bfloat16(v);
    return *reinterpret_cast<ushort*>(&h);
}

// ---------------- Kernel A: normalize rows -> bf16 + per-block compaction ----------------
// 256 blocks x 32 contiguous rows. One atomicAdd per block (spread out, not serialized).
// ridx slot order non-deterministic; per-row results are slot-invariant -> deterministic output.
__global__ __launch_bounds__(256) void prep_kernel(const float* __restrict__ feat,
                                                   const float* __restrict__ ious,
                                                   const int* __restrict__ labels,
                                                   ushort* __restrict__ fhi,
                                                   int* __restrict__ ridx,
                                                   int* __restrict__ nact) {
    const int wid  = threadIdx.x >> 6;
    const int lane = threadIdx.x & 63;
#pragma unroll
    for (int r8 = 0; r8 < 8; ++r8) {
        const int row = blockIdx.x * 32 + r8 * 4 + wid;
        const float4 x = reinterpret_cast<const float4*>(feat + (size_t)row * DIM)[lane];
        float ss = x.x * x.x + x.y * x.y + x.z * x.z + x.w * x.w;
#pragma unroll
        for (int off = 32; off; off >>= 1) ss += __shfl_xor(ss, off);
        const float inv = 1.0f / fmaxf(sqrtf(ss), 1e-12f);
        ushort4 h;
        h.x = f2bf(x.x * inv); h.y = f2bf(x.y * inv);
        h.z = f2bf(x.z * inv); h.w = f2bf(x.w * inv);
        reinterpret_cast<ushort4*>(fhi + (size_t)row * DIM)[lane] = h;
    }
    if (threadIdx.x < 64) {            // wave 0 compacts this block's 32 rows
        const int row = min(blockIdx.x * 32 + lane, N_ROWS - 1);
        const bool act = (lane < 32) && (labels[row] >= 0) && (ious[row] > 0.5f);
        const unsigned long long mb = __ballot(act);
        const int off = __popcll(mb & ((1ull << lane) - 1ull));
        const int tot = __popcll(mb);
        int base = 0;
        if (lane == 0 && tot) base = atomicAdd(nact, tot);
        base = __shfl(base, 0);
        if (act) ridx[base + off] = row;
    }
}

// ---------------- Kernel B: fused tiled sim + mask + fixed-max softmax partials ----------------
// grid = 1024: chunk = bid&15 (512 cols), rowblk = bid>>4 (128 active-row slots)
// B tile in MFMA-FRAGMENT ORDER (conflict-free, immediate-offset reads).
// TILE_C=64: 2 barriers per 64 cols (half the sync events of TILE_C=32).
// Counted-vmcnt: next tile's 8 loads stay in flight across compute.
// launch_bounds (256,3): (256,4) spills the 64-VGPR A-fragments (round-14 post-mortem).
__global__ __launch_bounds__(256, 3) void main_kernel(const ushort* __restrict__ fhi,
                                                      const float* __restrict__ ious,
                                                      const int* __restrict__ labels,
                                                      const int* __restrict__ ridx,
                                                      const int* __restrict__ nact,
                                                      float* __restrict__ ps_part,
                                                      float* __restrict__ as_part) {
    const int nactive = nact[0];
    const int bid   = blockIdx.x;
    const int rbase = (bid >> 4) * R_BLK;
    if (rbase >= nactive) return;      // uniform early-exit, before any barrier

    const int chunk = bid & (N_CHUNKS - 1);
    const int c0    = chunk * C_CHUNK;

    const int tid  = threadIdx.x;
    const int lane = tid & 63;
    const int w    = tid >> 6;          // 0..3
    const int lrow = lane & 15;
    const int kg   = lane >> 4;         // 0..3
    const int s0   = rbase + w * 32;    // this wave's first row-slot

    __shared__ bf16x8 bt[2][2048];          // 64 KB, double-buffered fragment-ordered B tile
    __shared__ int    lab_s[C_CHUNK];       // 2 KB
    __shared__ float  iou_s[C_CHUNK];       // 2 KB

    // stage column metadata for this chunk (2 per thread)
#pragma unroll
    for (int i = tid; i < C_CHUNK; i += 256) {
        lab_s[i] = labels[c0 + i];
        iou_s[i] = ious[c0 + i];
    }

    // A fragments: two 16-row tiles (gathered via ridx) x 256 k in registers
    bf16x8 av0[8], av1[8];
    {
        const int rowA0 = ridx[min(s0 + lrow,      nactive - 1)];
        const int rowA1 = ridx[min(s0 + 16 + lrow, nactive - 1)];
        const ushort* pa0 = fhi + (size_t)rowA0 * DIM + kg * 8;
        const ushort* pa1 = fhi + (size_t)rowA1 * DIM + kg * 8;
#pragma unroll
        for (int t = 0; t < 8; ++t) {
            av0[t] = *reinterpret_cast<const bf16x8*>(pa0 + t * 32);
            av1[t] = *reinterpret_cast<const bf16x8*>(pa1 + t * 32);
        }
    }

    // row metadata for the 8 row-slots this lane covers (C/D: col=lane&15, row=kg*4+reg)
    int rowm[8]; int labi[8]; float ioui[8]; int livem = 0;
#pragma unroll
    for (int m = 0; m < 8; ++m) {
        const int rt = m >> 2, r = m & 3;
        const int slot = s0 + rt * 16 + kg * 4 + r;
        const bool lv = slot < nactive;
        livem |= lv ? (1 << m) : 0;
        const int gi = ridx[min(slot, nactive - 1)];
        rowm[m] = gi;
        labi[m] = lv ? labels[gi] : -2;   // -2: matches no column label
        ioui[m] = ious[gi];
    }

    float ps[8], as_[8];
#pragma unroll
    for (int m = 0; m < 8; ++m) { ps[m] = 0.f; as_[m] = 0.f; }

    // staging in fragment order: LDS chunk L <- global fragment (colgroup g, t, lr, kg2)
    const char* fhib = (const char*)fhi;
    char* btb = (char*)&bt[0][0];
    auto stage = [&](int buf, int it) {
        const int jc = c0 + it * TILE_C;
#pragma unroll
        for (int iss = 0; iss < 8; ++iss) {
            const int L   = iss * 256 + tid;      // 0..2047
            const int g   = L >> 9;               // col-16-group 0..3
            const int rem = L & 511;
            const int t   = rem >> 6;
            const int lr  = (rem >> 2) & 15;
            const int kg2 = rem & 3;
            const char* src = fhib + (((size_t)(jc + g * 16 + lr)) << 9) + (kg2 * 16 + t * 64);
            char* dst = btb + buf * 32768 + iss * 4096 + tid * 16;
            gload_lds16(src, dst);
        }
    };

    stage(0, 0);
    __syncthreads();    // prologue: metadata ds_writes + tile0 all resident

    const float C1 = 14.42695041f;   // 10*log2(e): e = exp2(acc*C1 - C1) == exp(sim-10)
    int cur = 0;
    for (int it = 0; it < N_ITERS; ++it) {
        if (it + 1 < N_ITERS) {
            stage(cur ^ 1, it + 1);                       // 8 loads stay in flight across compute
            asm volatile("s_waitcnt vmcnt(8)" ::: "memory");  // drain tile `it` only
        } else {
            asm volatile("s_waitcnt vmcnt(0)" ::: "memory");  // last tile: full drain
        }
        __builtin_amdgcn_s_barrier();
        __builtin_amdgcn_sched_barrier(0);   // pin ds_reads below the barrier

        const int jcl = it * TILE_C;
        int   labj[4]; float iouj[4]; int colg[4];
#pragma unroll
        for (int g = 0; g < 4; ++g) {
            colg[g] = c0 + jcl + g * 16 + lrow;
            labj[g] = lab_s[jcl + g * 16 + lrow];
            iouj[g] = iou_s[jcl + g * 16 + lrow];
        }

        f32x4 acc0[4], acc1[4];
#pragma unroll
        for (int g = 0; g < 4; ++g) { acc0[g] = (f32x4){0.f,0.f,0.f,0.f}; acc1[g] = (f32x4){0.f,0.f,0.f,0.f}; }
        const char* lbase = btb + cur * 32768 + ((lrow * 4 + kg) << 4);
#pragma unroll
        for (int t = 0; t < 8; ++t) {
#pragma unroll
            for (int g = 0; g < 4; ++g) {
                bf16x8 b = *reinterpret_cast<const bf16x8*>(lbase + g * 8192 + t * 1024);
                acc0[g] = __builtin_amdgcn_mfma_f32_16x16x32_bf16(av0[t], b, acc0[g], 0, 0, 0);
                acc1[g] = __builtin_amdgcn_mfma_f32_16x16x32_bf16(av1[t], b, acc1[g], 0, 0, 0);
            }
        }

        // epilogue (active rows: hi_i true, ng_i false, fg_i true):
        //   pos = same && iouj>0.5 && |d|<0.2 && fgj && i!=j
        //   allm = (fgj && i!=j) && (ioum || !same)
#pragma unroll
        for (int rt = 0; rt < 2; ++rt) {
#pragma unroll
            for (int g = 0; g < 4; ++g) {
                const f32x4 acc = rt ? acc1[g] : acc0[g];
                const bool fgj = labj[g] >= 0;
                const bool hij = iouj[g] > 0.5f;
#pragma unroll
                for (int r = 0; r < 4; ++r) {
                    const int m  = rt * 4 + r;
                    const bool same = (labi[m] == labj[g]);
                    const bool ioum = hij && (fabsf(iouj[g] - ioui[m]) < 0.2f);
                    const bool pf   = fgj && (rowm[m] != colg[g]);
                    const bool pos  = same && ioum && pf;
                    const bool allm = pf && (ioum || !same);
                    const float e = allm ? exp2f(fmaf(acc[r], C1, -C1)) : 0.0f;
                    as_[m] += e;
                    ps[m]  += pos ? e : 0.0f;
                }
            }
        }
        __builtin_amdgcn_sched_barrier(0);
        __builtin_amdgcn_s_barrier();    // reads of buf `cur` done before it+2 overwrites it
        cur ^= 1;
    }

    // reduce over the 16 lanes (lrow) holding col-slices of the same rows
#pragma unroll
    for (int off = 1; off < 16; off <<= 1) {
#pragma unroll
        for (int m = 0; m < 8; ++m) {
            ps[m]  += __shfl_xor(ps[m], off);
            as_[m] += __shfl_xor(as_[m], off);
        }
    }

    if (lrow == 0) {
#pragma unroll
        for (int m = 0; m < 8; ++m) {
            if ((livem >> m) & 1) {
                const int idx = chunk * N_ROWS + rowm[m];
                ps_part[idx] = ps[m];
                as_part[idx] = as_[m];
            }
        }
    }
}

// ---------------- Kernel C: combine chunk partials -> per-row loss -> mean (fused) ----------------
__global__ __launch_bounds__(256) void combine_kernel(const float* __restrict__ ps_part,
                                                      const float* __restrict__ as_part,
                                                      const float* __restrict__ ious,
                                                      const int* __restrict__ labels,
                                                      float* __restrict__ partT,
                                                      float* __restrict__ partC,
                                                      int* __restrict__ done,
                                                      float* __restrict__ out) {
    const int tid = threadIdx.x;
    const int row = blockIdx.x * 256 + tid;
    const bool act = (labels[row] >= 0) && (ious[row] > 0.5f);
    float loss = 0.f, vld = 0.f;
    if (act) {
        float P = 0.f, A = 0.f;
#pragma unroll
        for (int c = 0; c < N_CHUNKS; ++c) {
            P += ps_part[c * N_ROWS + row];
            A += as_part[c * N_ROWS + row];
        }
        const float psc = fminf(fmaxf(P, 1e-6f), 1e6f);
        const float asc = fminf(fmaxf(A, 1e-6f), 1e6f);
        const bool valid = (P > 0.0f) && (A > P);
        loss = valid ? fminf(__logf(asc) - __logf(psc), 10.0f) : 0.0f;
        vld  = valid ? 1.0f : 0.0f;
    }
    float tl = loss, tc = vld;
#pragma unroll
    for (int off = 32; off; off >>= 1) { tl += __shfl_down(tl, off); tc += __shfl_down(tc, off); }
    __shared__ float sl[4], sc[4];
    const int wid = tid >> 6;
    if ((tid & 63) == 0) { sl[wid] = tl; sc[wid] = tc; }
    __syncthreads();
    if (tid == 0) {
        partT[blockIdx.x] = sl[0] + sl[1] + sl[2] + sl[3];
        partC[blockIdx.x] = sc[0] + sc[1] + sc[2] + sc[3];
        __threadfence();
        const int prev = atomicAdd(done, 1);
        if (prev == (int)gridDim.x - 1) {      // last block finalizes (fixed order: deterministic)
            __threadfence();
            float T = 0.f, C = 0.f;
#pragma unroll
            for (int b = 0; b < N_ROWS / 256; ++b) { T += partT[b]; C += partC[b]; }
            out[0] = (C > 0.f) ? (T / C) : 0.0f;
        }
    }
}

extern "C" void kernel_launch(void* const* d_in, const int* in_sizes, int n_in,
                              void* d_out, int out_size, void* d_ws, size_t ws_size,
                              hipStream_t stream) {
    const float* feat   = (const float*)d_in[0];
    const float* ious   = (const float*)d_in[1];
    const int*   labels = (const int*)d_in[2];
    float* out = (float*)d_out;

    ushort* fhi = (ushort*)d_ws;                                     // 4 MB
    float*  ps_part = (float*)(fhi + (size_t)N_ROWS * DIM);          // 512 KB
    float*  as_part = ps_part + (size_t)N_CHUNKS * N_ROWS;           // 512 KB
    int*    ridx = (int*)(as_part + (size_t)N_CHUNKS * N_ROWS);      // 32 KB
    int*    ctrs = ridx + N_ROWS;                                    // nact, done
    float*  partT = (float*)(ctrs + 2);                              // 32 floats
    float*  partC = partT + (N_ROWS / 256);                          // 32 floats

    hipMemsetAsync(ctrs, 0, 2 * sizeof(int), stream);
    prep_kernel<<<256, 256, 0, stream>>>(feat, ious, labels, fhi, ridx, ctrs);
    main_kernel<<<(N_ROWS / R_BLK) * N_CHUNKS, 256, 0, stream>>>(fhi, ious, labels,
                                                                 ridx, ctrs, ps_part, as_part);
    combine_kernel<<<N_ROWS / 256, 256, 0, stream>>>(ps_part, as_part, ious, labels,
                                                     partT, partC, ctrs + 1, out);
}

// Round 23
// 57.067 us; speedup vs baseline: 1.7727x; 1.0586x over previous
//
#include <hip/hip_runtime.h>
#include <hip/hip_bf16.h>

#define N_ROWS 8192
#define DIM 256
#define R_BLK 64           // row-slots per block (4 waves x 16) -> ~976 active blocks, 4/CU
#define C_CHUNK 512        // cols per block
#define TILE_C 32          // cols per LDS tile
#define N_CHUNKS 16
#define N_ITERS (C_CHUNK / TILE_C)   // 16

typedef __attribute__((ext_vector_type(4))) float f32x4;
typedef __attribute__((ext_vector_type(8))) short bf16x8;

__device__ __forceinline__ void gload_lds16(const void* g, void* l) {
    using gv = const __attribute__((address_space(1))) void*;
    using sv = __attribute__((address_space(3))) void*;
    __builtin_amdgcn_global_load_lds((gv)g, (sv)l, 16, 0, 0);
}

__device__ __forceinline__ ushort f2bf(float v) {
    __hip_bfloat16 h = __float2bfloat16(v);
    return *reinterpret_cast<ushort*>(&h);
}

// ---------------- Kernel A: normalize rows -> bf16 + per-block compaction ----------------
// 256 blocks x 32 contiguous rows. One atomicAdd per block (spread out, not serialized).
// ridx slot order non-deterministic; per-row results are slot-invariant -> deterministic output.
__global__ __launch_bounds__(256) void prep_kernel(const float* __restrict__ feat,
                                                   const float* __restrict__ ious,
                                                   const int* __restrict__ labels,
                                                   ushort* __restrict__ fhi,
                                                   int* __restrict__ ridx,
                                                   int* __restrict__ nact) {
    const int wid  = threadIdx.x >> 6;
    const int lane = threadIdx.x & 63;
#pragma unroll
    for (int r8 = 0; r8 < 8; ++r8) {
        const int row = blockIdx.x * 32 + r8 * 4 + wid;
        const float4 x = reinterpret_cast<const float4*>(feat + (size_t)row * DIM)[lane];
        float ss = x.x * x.x + x.y * x.y + x.z * x.z + x.w * x.w;
#pragma unroll
        for (int off = 32; off; off >>= 1) ss += __shfl_xor(ss, off);
        const float inv = 1.0f / fmaxf(sqrtf(ss), 1e-12f);
        ushort4 h;
        h.x = f2bf(x.x * inv); h.y = f2bf(x.y * inv);
        h.z = f2bf(x.z * inv); h.w = f2bf(x.w * inv);
        reinterpret_cast<ushort4*>(fhi + (size_t)row * DIM)[lane] = h;
    }
    if (threadIdx.x < 64) {            // wave 0 compacts this block's 32 rows
        const int row = min(blockIdx.x * 32 + lane, N_ROWS - 1);
        const bool act = (lane < 32) && (labels[row] >= 0) && (ious[row] > 0.5f);
        const unsigned long long mb = __ballot(act);
        const int off = __popcll(mb & ((1ull << lane) - 1ull));
        const int tot = __popcll(mb);
        int base = 0;
        if (lane == 0 && tot) base = atomicAdd(nact, tot);
        base = __shfl(base, 0);
        if (act) ridx[base + off] = row;
    }
}

// ---------------- Kernel B: fused tiled sim + mask + fixed-max softmax partials ----------------
// grid = 2048: chunk = bid&15 (512 cols), rowblk = bid>>4 (64 active-row slots, 16/wave)
// B tile in MFMA-FRAGMENT ORDER (conflict-free, immediate-offset reads).
// Counted-vmcnt two-barrier pipeline. launch_bounds (256,4): A-frags now only 32 VGPR
// (16 rows/wave), est ~100 total -> fits cap 128 without the round-14 spill.
__global__ __launch_bounds__(256, 4) void main_kernel(const ushort* __restrict__ fhi,
                                                      const float* __restrict__ ious,
                                                      const int* __restrict__ labels,
                                                      const int* __restrict__ ridx,
                                                      const int* __restrict__ nact,
                                                      float* __restrict__ ps_part,
                                                      float* __restrict__ as_part) {
    const int nactive = nact[0];
    const int bid   = blockIdx.x;
    const int rbase = (bid >> 4) * R_BLK;
    if (rbase >= nactive) return;      // uniform early-exit, before any barrier

    const int chunk = bid & (N_CHUNKS - 1);
    const int c0    = chunk * C_CHUNK;

    const int tid  = threadIdx.x;
    const int lane = tid & 63;
    const int w    = tid >> 6;          // 0..3
    const int lrow = lane & 15;
    const int kg   = lane >> 4;         // 0..3
    const int s0   = rbase + w * 16;    // this wave's first row-slot

    __shared__ bf16x8 bt[2][1024];          // 32 KB, double-buffered fragment-ordered B tile
    __shared__ int    lab_s[C_CHUNK];       // 2 KB
    __shared__ float  iou_s[C_CHUNK];       // 2 KB

    // stage column metadata for this chunk (2 per thread)
#pragma unroll
    for (int i = tid; i < C_CHUNK; i += 256) {
        lab_s[i] = labels[c0 + i];
        iou_s[i] = ious[c0 + i];
    }

    // A fragments: one 16-row tile (gathered via ridx) x 256 k in registers (32 VGPR)
    bf16x8 av[8];
    {
        const int rowA = ridx[min(s0 + lrow, nactive - 1)];
        const ushort* pa = fhi + (size_t)rowA * DIM + kg * 8;
#pragma unroll
        for (int t = 0; t < 8; ++t) av[t] = *reinterpret_cast<const bf16x8*>(pa + t * 32);
    }

    // row metadata for the 4 row-slots this lane covers (C/D: col=lane&15, row=kg*4+r)
    int rowm[4]; int labi[4]; float ioui[4]; int livem = 0;
#pragma unroll
    for (int m = 0; m < 4; ++m) {
        const int slot = s0 + kg * 4 + m;
        const bool lv = slot < nactive;
        livem |= lv ? (1 << m) : 0;
        const int gi = ridx[min(slot, nactive - 1)];
        rowm[m] = gi;
        labi[m] = lv ? labels[gi] : -2;   // -2: matches no column label
        ioui[m] = ious[gi];
    }

    float ps[4] = {0.f,0.f,0.f,0.f}, as_[4] = {0.f,0.f,0.f,0.f};

    // staging in fragment order: LDS chunk L <- global fragment (half,t,lr,kg2)
    const char* fhib = (const char*)fhi;
    char* btb = (char*)&bt[0][0];
    auto stage = [&](int buf, int it) {
        const int jc = c0 + it * TILE_C;
#pragma unroll
        for (int iss = 0; iss < 4; ++iss) {
            const int L    = iss * 256 + tid;      // 0..1023
            const int half = L >> 9;
            const int rem  = L & 511;
            const int t    = rem >> 6;
            const int lr   = (rem >> 2) & 15;
            const int kg2  = rem & 3;
            const char* src = fhib + (((size_t)(jc + half * 16 + lr)) << 9) + (kg2 * 16 + t * 64);
            char* dst = btb + buf * 16384 + iss * 4096 + tid * 16;
            gload_lds16(src, dst);
        }
    };

    stage(0, 0);
    __syncthreads();    // prologue: metadata ds_writes + tile0 all resident

    const float C1 = 14.42695041f;   // 10*log2(e): e = exp2(acc*C1 - C1) == exp(sim-10)
    int cur = 0;
    for (int it = 0; it < N_ITERS; ++it) {
        if (it + 1 < N_ITERS) {
            stage(cur ^ 1, it + 1);                       // 4 loads stay in flight across compute
            asm volatile("s_waitcnt vmcnt(4)" ::: "memory");  // drain tile `it` only
        } else {
            asm volatile("s_waitcnt vmcnt(0)" ::: "memory");  // last tile: full drain
        }
        __builtin_amdgcn_s_barrier();
        __builtin_amdgcn_sched_barrier(0);   // pin ds_reads below the barrier

        const int jcl = it * TILE_C;
        const int colg0 = c0 + jcl + lrow;
        const int colg1 = colg0 + 16;
        const int labj0 = lab_s[jcl + lrow];
        const int labj1 = lab_s[jcl + 16 + lrow];
        const float iouj0 = iou_s[jcl + lrow];
        const float iouj1 = iou_s[jcl + 16 + lrow];

        f32x4 acc0 = {0.f,0.f,0.f,0.f}, acc1 = {0.f,0.f,0.f,0.f};
        const char* lbase = btb + cur * 16384 + ((lrow * 4 + kg) << 4);
#pragma unroll
        for (int t = 0; t < 8; ++t) {
            bf16x8 b0 = *reinterpret_cast<const bf16x8*>(lbase + t * 1024);
            bf16x8 b1 = *reinterpret_cast<const bf16x8*>(lbase + 8192 + t * 1024);
            acc0 = __builtin_amdgcn_mfma_f32_16x16x32_bf16(av[t], b0, acc0, 0, 0, 0);
            acc1 = __builtin_amdgcn_mfma_f32_16x16x32_bf16(av[t], b1, acc1, 0, 0, 0);
        }

        // epilogue (active rows: hi_i true, ng_i false, fg_i true):
        //   pos = same && iouj>0.5 && |d|<0.2 && fgj && i!=j
        //   allm = (fgj && i!=j) && (ioum || !same)
#pragma unroll
        for (int half = 0; half < 2; ++half) {
            const int colg = half ? colg1 : colg0;
            const int labj = half ? labj1 : labj0;
            const float iouj = half ? iouj1 : iouj0;
            const f32x4 acc = half ? acc1 : acc0;
            const bool fgj = labj >= 0;
            const bool hij = iouj > 0.5f;
#pragma unroll
            for (int m = 0; m < 4; ++m) {
                const bool same = (labi[m] == labj);
                const bool ioum = hij && (fabsf(iouj - ioui[m]) < 0.2f);
                const bool pf   = fgj && (rowm[m] != colg);
                const bool pos  = same && ioum && pf;
                const bool allm = pf && (ioum || !same);
                const float e = allm ? exp2f(fmaf(acc[m], C1, -C1)) : 0.0f;
                as_[m] += e;
                ps[m]  += pos ? e : 0.0f;
            }
        }
        __builtin_amdgcn_sched_barrier(0);
        __builtin_amdgcn_s_barrier();    // reads of buf `cur` done before it+2 overwrites it
        cur ^= 1;
    }

    // reduce over the 16 lanes (lrow) holding col-slices of the same rows
#pragma unroll
    for (int off = 1; off < 16; off <<= 1) {
#pragma unroll
        for (int m = 0; m < 4; ++m) {
            ps[m]  += __shfl_xor(ps[m], off);
            as_[m] += __shfl_xor(as_[m], off);
        }
    }

    if (lrow == 0) {
#pragma unroll
        for (int m = 0; m < 4; ++m) {
            if ((livem >> m) & 1) {
                const int idx = chunk * N_ROWS + rowm[m];
                ps_part[idx] = ps[m];
                as_part[idx] = as_[m];
            }
        }
    }
}

// ---------------- Kernel C: combine chunk partials -> per-row loss -> mean (fused) ----------------
__global__ __launch_bounds__(256) void combine_kernel(const float* __restrict__ ps_part,
                                                      const float* __restrict__ as_part,
                                                      const float* __restrict__ ious,
                                                      const int* __restrict__ labels,
                                                      float* __restrict__ partT,
                                                      float* __restrict__ partC,
                                                      int* __restrict__ done,
                                                      float* __restrict__ out) {
    const int tid = threadIdx.x;
    const int row = blockIdx.x * 256 + tid;
    const bool act = (labels[row] >= 0) && (ious[row] > 0.5f);
    float loss = 0.f, vld = 0.f;
    if (act) {
        float P = 0.f, A = 0.f;
#pragma unroll
        for (int c = 0; c < N_CHUNKS; ++c) {
            P += ps_part[c * N_ROWS + row];
            A += as_part[c * N_ROWS + row];
        }
        const float psc = fminf(fmaxf(P, 1e-6f), 1e6f);
        const float asc = fminf(fmaxf(A, 1e-6f), 1e6f);
        const bool valid = (P > 0.0f) && (A > P);
        loss = valid ? fminf(__logf(asc) - __logf(psc), 10.0f) : 0.0f;
        vld  = valid ? 1.0f : 0.0f;
    }
    float tl = loss, tc = vld;
#pragma unroll
    for (int off = 32; off; off >>= 1) { tl += __shfl_down(tl, off); tc += __shfl_down(tc, off); }
    __shared__ float sl[4], sc[4];
    const int wid = tid >> 6;
    if ((tid & 63) == 0) { sl[wid] = tl; sc[wid] = tc; }
    __syncthreads();
    if (tid == 0) {
        partT[blockIdx.x] = sl[0] + sl[1] + sl[2] + sl[3];
        partC[blockIdx.x] = sc[0] + sc[1] + sc[2] + sc[3];
        __threadfence();
        const int prev = atomicAdd(done, 1);
        if (prev == (int)gridDim.x - 1) {      // last block finalizes (fixed order: deterministic)
            __threadfence();
            float T = 0.f, C = 0.f;
#pragma unroll
            for (int b = 0; b < N_ROWS / 256; ++b) { T += partT[b]; C += partC[b]; }
            out[0] = (C > 0.f) ? (T / C) : 0.0f;
        }
    }
}

extern "C" void kernel_launch(void* const* d_in, const int* in_sizes, int n_in,
                              void* d_out, int out_size, void* d_ws, size_t ws_size,
                              hipStream_t stream) {
    const float* feat   = (const float*)d_in[0];
    const float* ious   = (const float*)d_in[1];
    const int*   labels = (const int*)d_in[2];
    float* out = (float*)d_out;

    ushort* fhi = (ushort*)d_ws;                                     // 4 MB
    float*  ps_part = (float*)(fhi + (size_t)N_ROWS * DIM);          // 512 KB
    float*  as_part = ps_part + (size_t)N_CHUNKS * N_ROWS;           // 512 KB
    int*    ridx = (int*)(as_part + (size_t)N_CHUNKS * N_ROWS);      // 32 KB
    int*    ctrs = ridx + N_ROWS;                                    // nact, done
    float*  partT = (float*)(ctrs + 2);                              // 32 floats
    float*  partC = partT + (N_ROWS / 256);                          // 32 floats

    hipMemsetAsync(ctrs, 0, 2 * sizeof(int), stream);
    prep_kernel<<<256, 256, 0, stream>>>(feat, ious, labels, fhi, ridx, ctrs);
    main_kernel<<<(N_ROWS / R_BLK) * N_CHUNKS, 256, 0, stream>>>(fhi, ious, labels,
                                                                 ridx, ctrs, ps_part, as_part);
    combine_kernel<<<N_ROWS / 256, 256, 0, stream>>>(ps_part, as_part, ious, labels,
                                                     partT, partC, ctrs + 1, out);
}

// Round 24
// 51.587 us; speedup vs baseline: 1.9610x; 1.1062x over previous
//
#include <hip/hip_runtime.h>
#include <hip/hip_bf16.h>

#define N_ROWS 8192
#define DIM 256
#define R_BLK 64           // row-slots per block (4 waves x 16)
#define C_CHUNK 512        // cols per block
#define TILE_C 32          // cols per LDS tile
#define N_CHUNKS 16
#define N_ITERS (C_CHUNK / TILE_C)   // 16
#define N_PBLK 256         // prep blocks (32 rows each)

typedef __attribute__((ext_vector_type(4))) float f32x4;
typedef __attribute__((ext_vector_type(8))) short bf16x8;

__device__ __forceinline__ void gload_lds16(const void* g, void* l) {
    using gv = const __attribute__((address_space(1))) void*;
    using sv = __attribute__((address_space(3))) void*;
    __builtin_amdgcn_global_load_lds((gv)g, (sv)l, 16, 0, 0);
}

__device__ __forceinline__ ushort f2bf(float v) {
    __hip_bfloat16 h = __float2bfloat16(v);
    return *reinterpret_cast<ushort*>(&h);
}

// ---------------- Kernel A: normalize rows -> bf16 + per-block local compaction ----------------
// 256 blocks x 32 rows. NO atomics, NO pre-zeroed counters: block b writes cnt[b] and its
// active rows locally compacted at raw[b*32..]. Block 0 zeroes `done` for combine (stream-ordered).
// Fully deterministic.
__global__ __launch_bounds__(256) void prep_kernel(const float* __restrict__ feat,
                                                   const float* __restrict__ ious,
                                                   const int* __restrict__ labels,
                                                   ushort* __restrict__ fhi,
                                                   int* __restrict__ raw,
                                                   int* __restrict__ cnt,
                                                   int* __restrict__ done) {
    if (blockIdx.x == 0 && threadIdx.x == 0) done[0] = 0;
    const int wid  = threadIdx.x >> 6;
    const int lane = threadIdx.x & 63;
#pragma unroll
    for (int r8 = 0; r8 < 8; ++r8) {
        const int row = blockIdx.x * 32 + r8 * 4 + wid;
        const float4 x = reinterpret_cast<const float4*>(feat + (size_t)row * DIM)[lane];
        float ss = x.x * x.x + x.y * x.y + x.z * x.z + x.w * x.w;
#pragma unroll
        for (int off = 32; off; off >>= 1) ss += __shfl_xor(ss, off);
        const float inv = 1.0f / fmaxf(sqrtf(ss), 1e-12f);
        ushort4 h;
        h.x = f2bf(x.x * inv); h.y = f2bf(x.y * inv);
        h.z = f2bf(x.z * inv); h.w = f2bf(x.w * inv);
        reinterpret_cast<ushort4*>(fhi + (size_t)row * DIM)[lane] = h;
    }
    if (threadIdx.x < 64) {            // wave 0: local compaction of this block's 32 rows
        const int row = blockIdx.x * 32 + (lane & 31);
        const bool act = (lane < 32) && (labels[row] >= 0) && (ious[row] > 0.5f);
        const unsigned long long mb = __ballot(act);
        const int off = __popcll(mb & ((1ull << lane) - 1ull));
        if (act) raw[blockIdx.x * 32 + off] = row;
        if (lane == 0) cnt[blockIdx.x] = __popcll(mb);
    }
}

// ---------------- Kernel B: fused tiled sim + mask + fixed-max softmax partials ----------------
// grid = 2048: chunk = bid&15 (512 cols), rowblk = bid>>4 (64 active-row slots, 16/wave).
// Prologue: block-local 256-entry prefix scan of cnt[] -> slot->row mapping (deterministic).
// B tile in MFMA-FRAGMENT ORDER (conflict-free, immediate-offset reads).
// Counted-vmcnt two-barrier pipeline. launch_bounds (256,4): A-frags 32 VGPR, no spill.
__global__ __launch_bounds__(256, 4) void main_kernel(const ushort* __restrict__ fhi,
                                                      const float* __restrict__ ious,
                                                      const int* __restrict__ labels,
                                                      const int* __restrict__ raw,
                                                      const int* __restrict__ cnt,
                                                      float* __restrict__ ps_part,
                                                      float* __restrict__ as_part) {
    const int tid  = threadIdx.x;

    __shared__ int sc[N_PBLK];       // inclusive scan workspace
    __shared__ int sex[N_PBLK + 1];  // exclusive prefix
    sc[tid] = cnt[tid];
    __syncthreads();
#pragma unroll
    for (int d = 1; d < N_PBLK; d <<= 1) {
        const int add = (tid >= d) ? sc[tid - d] : 0;
        __syncthreads();
        sc[tid] += add;
        __syncthreads();
    }
    if (tid == 0) sex[0] = 0;
    sex[tid + 1] = sc[tid];
    __syncthreads();
    const int nactive = sex[N_PBLK];

    const int bid   = blockIdx.x;
    const int rbase = (bid >> 4) * R_BLK;
    if (rbase >= nactive) return;      // block-uniform exit (after uniform scan barriers)

    const int chunk = bid & (N_CHUNKS - 1);
    const int c0    = chunk * C_CHUNK;

    const int lane = tid & 63;
    const int w    = tid >> 6;          // 0..3
    const int lrow = lane & 15;
    const int kg   = lane >> 4;         // 0..3
    const int s0   = rbase + w * 16;    // this wave's first row-slot

    // slot -> original row (binary search over exclusive prefix)
    auto slot2row = [&](int s) {
        int lo = 0, hi = N_PBLK;
#pragma unroll
        for (int step = 0; step < 8; ++step) {
            const int mid = (lo + hi) >> 1;
            if (sex[mid] <= s) lo = mid; else hi = mid;
        }
        return raw[lo * 32 + (s - sex[lo])];
    };

    __shared__ bf16x8 bt[2][1024];          // 32 KB, double-buffered fragment-ordered B tile
    __shared__ int    lab_s[C_CHUNK];       // 2 KB
    __shared__ float  iou_s[C_CHUNK];       // 2 KB

    // stage column metadata for this chunk (2 per thread)
#pragma unroll
    for (int i = tid; i < C_CHUNK; i += 256) {
        lab_s[i] = labels[c0 + i];
        iou_s[i] = ious[c0 + i];
    }

    // A fragments: one 16-row tile (gathered) x 256 k in registers (32 VGPR)
    bf16x8 av[8];
    {
        const int rowA = slot2row(min(s0 + lrow, nactive - 1));
        const ushort* pa = fhi + (size_t)rowA * DIM + kg * 8;
#pragma unroll
        for (int t = 0; t < 8; ++t) av[t] = *reinterpret_cast<const bf16x8*>(pa + t * 32);
    }

    // row metadata for the 4 row-slots this lane covers (C/D: col=lane&15, row=kg*4+r)
    int rowm[4]; int labi[4]; float ioui[4]; int livem = 0;
#pragma unroll
    for (int m = 0; m < 4; ++m) {
        const int slot = s0 + kg * 4 + m;
        const bool lv = slot < nactive;
        livem |= lv ? (1 << m) : 0;
        const int gi = slot2row(min(slot, nactive - 1));
        rowm[m] = gi;
        labi[m] = lv ? labels[gi] : -2;   // -2: matches no column label
        ioui[m] = ious[gi];
    }

    float ps[4] = {0.f,0.f,0.f,0.f}, as_[4] = {0.f,0.f,0.f,0.f};

    // staging in fragment order: LDS chunk L <- global fragment (half,t,lr,kg2)
    const char* fhib = (const char*)fhi;
    char* btb = (char*)&bt[0][0];
    auto stage = [&](int buf, int it) {
        const int jc = c0 + it * TILE_C;
#pragma unroll
        for (int iss = 0; iss < 4; ++iss) {
            const int L    = iss * 256 + tid;      // 0..1023
            const int half = L >> 9;
            const int rem  = L & 511;
            const int t    = rem >> 6;
            const int lr   = (rem >> 2) & 15;
            const int kg2  = rem & 3;
            const char* src = fhib + (((size_t)(jc + half * 16 + lr)) << 9) + (kg2 * 16 + t * 64);
            char* dst = btb + buf * 16384 + iss * 4096 + tid * 16;
            gload_lds16(src, dst);
        }
    };

    stage(0, 0);
    __syncthreads();    // prologue: metadata ds_writes + tile0 all resident

    const float C1 = 14.42695041f;   // 10*log2(e): e = exp2(acc*C1 - C1) == exp(sim-10)
    int cur = 0;
    for (int it = 0; it < N_ITERS; ++it) {
        if (it + 1 < N_ITERS) {
            stage(cur ^ 1, it + 1);                       // 4 loads stay in flight across compute
            asm volatile("s_waitcnt vmcnt(4)" ::: "memory");  // drain tile `it` only
        } else {
            asm volatile("s_waitcnt vmcnt(0)" ::: "memory");  // last tile: full drain
        }
        __builtin_amdgcn_s_barrier();
        __builtin_amdgcn_sched_barrier(0);   // pin ds_reads below the barrier

        const int jcl = it * TILE_C;
        const int colg0 = c0 + jcl + lrow;
        const int colg1 = colg0 + 16;
        const int labj0 = lab_s[jcl + lrow];
        const int labj1 = lab_s[jcl + 16 + lrow];
        const float iouj0 = iou_s[jcl + lrow];
        const float iouj1 = iou_s[jcl + 16 + lrow];

        f32x4 acc0 = {0.f,0.f,0.f,0.f}, acc1 = {0.f,0.f,0.f,0.f};
        const char* lbase = btb + cur * 16384 + ((lrow * 4 + kg) << 4);
#pragma unroll
        for (int t = 0; t < 8; ++t) {
            bf16x8 b0 = *reinterpret_cast<const bf16x8*>(lbase + t * 1024);
            bf16x8 b1 = *reinterpret_cast<const bf16x8*>(lbase + 8192 + t * 1024);
            acc0 = __builtin_amdgcn_mfma_f32_16x16x32_bf16(av[t], b0, acc0, 0, 0, 0);
            acc1 = __builtin_amdgcn_mfma_f32_16x16x32_bf16(av[t], b1, acc1, 0, 0, 0);
        }

        // epilogue (active rows: hi_i true, ng_i false, fg_i true):
        //   pos = same && iouj>0.5 && |d|<0.2 && fgj && i!=j
        //   allm = (fgj && i!=j) && (ioum || !same)
#pragma unroll
        for (int half = 0; half < 2; ++half) {
            const int colg = half ? colg1 : colg0;
            const int labj = half ? labj1 : labj0;
            const float iouj = half ? iouj1 : iouj0;
            const f32x4 acc = half ? acc1 : acc0;
            const bool fgj = labj >= 0;
            const bool hij = iouj > 0.5f;
#pragma unroll
            for (int m = 0; m < 4; ++m) {
                const bool same = (labi[m] == labj);
                const bool ioum = hij && (fabsf(iouj - ioui[m]) < 0.2f);
                const bool pf   = fgj && (rowm[m] != colg);
                const bool pos  = same && ioum && pf;
                const bool allm = pf && (ioum || !same);
                const float e = allm ? exp2f(fmaf(acc[m], C1, -C1)) : 0.0f;
                as_[m] += e;
                ps[m]  += pos ? e : 0.0f;
            }
        }
        __builtin_amdgcn_sched_barrier(0);
        __builtin_amdgcn_s_barrier();    // reads of buf `cur` done before it+2 overwrites it
        cur ^= 1;
    }

    // reduce over the 16 lanes (lrow) holding col-slices of the same rows
#pragma unroll
    for (int off = 1; off < 16; off <<= 1) {
#pragma unroll
        for (int m = 0; m < 4; ++m) {
            ps[m]  += __shfl_xor(ps[m], off);
            as_[m] += __shfl_xor(as_[m], off);
        }
    }

    if (lrow == 0) {
#pragma unroll
        for (int m = 0; m < 4; ++m) {
            if ((livem >> m) & 1) {
                const int idx = chunk * N_ROWS + rowm[m];
                ps_part[idx] = ps[m];
                as_part[idx] = as_[m];
            }
        }
    }
}

// ---------------- Kernel C: combine chunk partials -> per-row loss -> mean (fused) ----------------
__global__ __launch_bounds__(256) void combine_kernel(const float* __restrict__ ps_part,
                                                      const float* __restrict__ as_part,
                                                      const float* __restrict__ ious,
                                                      const int* __restrict__ labels,
                                                      float* __restrict__ partT,
                                                      float* __restrict__ partC,
                                                      int* __restrict__ done,
                                                      float* __restrict__ out) {
    const int tid = threadIdx.x;
    const int row = blockIdx.x * 256 + tid;
    const bool act = (labels[row] >= 0) && (ious[row] > 0.5f);
    float loss = 0.f, vld = 0.f;
    if (act) {
        float P = 0.f, A = 0.f;
#pragma unroll
        for (int c = 0; c < N_CHUNKS; ++c) {
            P += ps_part[c * N_ROWS + row];
            A += as_part[c * N_ROWS + row];
        }
        const float psc = fminf(fmaxf(P, 1e-6f), 1e6f);
        const float asc = fminf(fmaxf(A, 1e-6f), 1e6f);
        const bool valid = (P > 0.0f) && (A > P);
        loss = valid ? fminf(__logf(asc) - __logf(psc), 10.0f) : 0.0f;
        vld  = valid ? 1.0f : 0.0f;
    }
    float tl = loss, tc = vld;
#pragma unroll
    for (int off = 32; off; off >>= 1) { tl += __shfl_down(tl, off); tc += __shfl_down(tc, off); }
    __shared__ float sl[4], sc4[4];
    const int wid = tid >> 6;
    if ((tid & 63) == 0) { sl[wid] = tl; sc4[wid] = tc; }
    __syncthreads();
    if (tid == 0) {
        partT[blockIdx.x] = sl[0] + sl[1] + sl[2] + sl[3];
        partC[blockIdx.x] = sc4[0] + sc4[1] + sc4[2] + sc4[3];
        __threadfence();
        const int prev = atomicAdd(done, 1);
        if (prev == (int)gridDim.x - 1) {      // last block finalizes (fixed order: deterministic)
            __threadfence();
            float T = 0.f, C = 0.f;
#pragma unroll
            for (int b = 0; b < N_ROWS / 256; ++b) { T += partT[b]; C += partC[b]; }
            out[0] = (C > 0.f) ? (T / C) : 0.0f;
        }
    }
}

extern "C" void kernel_launch(void* const* d_in, const int* in_sizes, int n_in,
                              void* d_out, int out_size, void* d_ws, size_t ws_size,
                              hipStream_t stream) {
    const float* feat   = (const float*)d_in[0];
    const float* ious   = (const float*)d_in[1];
    const int*   labels = (const int*)d_in[2];
    float* out = (float*)d_out;

    ushort* fhi = (ushort*)d_ws;                                     // 4 MB
    float*  ps_part = (float*)(fhi + (size_t)N_ROWS * DIM);          // 512 KB
    float*  as_part = ps_part + (size_t)N_CHUNKS * N_ROWS;           // 512 KB
    int*    raw  = (int*)(as_part + (size_t)N_CHUNKS * N_ROWS);      // 32 KB
    int*    cnt  = raw + N_ROWS;                                     // 1 KB
    int*    done = cnt + N_PBLK;                                     // 4 B
    float*  partT = (float*)(done + 1);                              // 32 floats
    float*  partC = partT + (N_ROWS / 256);                          // 32 floats

    prep_kernel<<<N_PBLK, 256, 0, stream>>>(feat, ious, labels, fhi, raw, cnt, done);
    main_kernel<<<(N_ROWS / R_BLK) * N_CHUNKS, 256, 0, stream>>>(fhi, ious, labels,
                                                                 raw, cnt, ps_part, as_part);
    combine_kernel<<<N_ROWS / 256, 256, 0, stream>>>(ps_part, as_part, ious, labels,
                                                     partT, partC, done, out);
}

// Round 25
// 51.221 us; speedup vs baseline: 1.9750x; 1.0071x over previous
//
#include <hip/hip_runtime.h>
#include <hip/hip_bf16.h>

#define N_ROWS 8192
#define DIM 256
#define R_BLK 64           // row-slots per block (4 waves x 16)
#define C_CHUNK 512        // cols per block
#define TILE_C 32          // cols per LDS tile
#define N_CHUNKS 16
#define N_ITERS (C_CHUNK / TILE_C)   // 16
#define N_PBLK 256         // prep blocks (32 rows each)

typedef __attribute__((ext_vector_type(4))) float f32x4;
typedef __attribute__((ext_vector_type(8))) short bf16x8;

__device__ __forceinline__ void gload_lds16(const void* g, void* l) {
    using gv = const __attribute__((address_space(1))) void*;
    using sv = __attribute__((address_space(3))) void*;
    __builtin_amdgcn_global_load_lds((gv)g, (sv)l, 16, 0, 0);
}

__device__ __forceinline__ ushort f2bf(float v) {
    __hip_bfloat16 h = __float2bfloat16(v);
    return *reinterpret_cast<ushort*>(&h);
}

// ---------------- Kernel A: normalize rows -> bf16 + per-block local compaction ----------------
// 256 blocks x 32 rows. NO atomics, NO pre-zeroed counters: block b writes cnt[b] and its
// active rows locally compacted at raw[b*32..]. Block 0 zeroes `done` for combine (stream-ordered).
// Fully deterministic.
__global__ __launch_bounds__(256) void prep_kernel(const float* __restrict__ feat,
                                                   const float* __restrict__ ious,
                                                   const int* __restrict__ labels,
                                                   ushort* __restrict__ fhi,
                                                   int* __restrict__ raw,
                                                   int* __restrict__ cnt,
                                                   int* __restrict__ done) {
    if (blockIdx.x == 0 && threadIdx.x == 0) done[0] = 0;
    const int wid  = threadIdx.x >> 6;
    const int lane = threadIdx.x & 63;
#pragma unroll
    for (int r8 = 0; r8 < 8; ++r8) {
        const int row = blockIdx.x * 32 + r8 * 4 + wid;
        const float4 x = reinterpret_cast<const float4*>(feat + (size_t)row * DIM)[lane];
        float ss = x.x * x.x + x.y * x.y + x.z * x.z + x.w * x.w;
#pragma unroll
        for (int off = 32; off; off >>= 1) ss += __shfl_xor(ss, off);
        const float inv = 1.0f / fmaxf(sqrtf(ss), 1e-12f);
        ushort4 h;
        h.x = f2bf(x.x * inv); h.y = f2bf(x.y * inv);
        h.z = f2bf(x.z * inv); h.w = f2bf(x.w * inv);
        reinterpret_cast<ushort4*>(fhi + (size_t)row * DIM)[lane] = h;
    }
    if (threadIdx.x < 64) {            // wave 0: local compaction of this block's 32 rows
        const int row = blockIdx.x * 32 + (lane & 31);
        const bool act = (lane < 32) && (labels[row] >= 0) && (ious[row] > 0.5f);
        const unsigned long long mb = __ballot(act);
        const int off = __popcll(mb & ((1ull << lane) - 1ull));
        if (act) raw[blockIdx.x * 32 + off] = row;
        if (lane == 0) cnt[blockIdx.x] = __popcll(mb);
    }
}

// ---------------- Kernel B: fused tiled sim + mask + fixed-max softmax partials ----------------
// grid = 2048: chunk = bid&15 (512 cols), rowblk = bid>>4 (64 active-row slots, 16/wave).
// Prologue: WAVE-0 SHUFFLE SCAN of cnt[] (one block barrier, not 17) -> sex[] prefix;
// dead blocks exit after ~40 ops. B tile in MFMA-FRAGMENT ORDER. Counted-vmcnt pipeline.
__global__ __launch_bounds__(256, 4) void main_kernel(const ushort* __restrict__ fhi,
                                                      const float* __restrict__ ious,
                                                      const int* __restrict__ labels,
                                                      const int* __restrict__ raw,
                                                      const int* __restrict__ cnt,
                                                      float* __restrict__ ps_part,
                                                      float* __restrict__ as_part) {
    const int tid  = threadIdx.x;
    const int lane = tid & 63;

    __shared__ int sex[N_PBLK + 1];  // exclusive prefix of cnt
    if (tid < 64) {                  // wave-0 scan: 4 cnt values per lane
        const int v0 = cnt[lane * 4 + 0];
        const int v1 = cnt[lane * 4 + 1];
        const int v2 = cnt[lane * 4 + 2];
        const int v3 = cnt[lane * 4 + 3];
        const int s01 = v0 + v1, s012 = s01 + v2;
        const int lsum = s012 + v3;
        int inc = lsum;
#pragma unroll
        for (int off = 1; off < 64; off <<= 1) {
            const int t = __shfl_up(inc, off);
            if (lane >= off) inc += t;
        }
        const int base = inc - lsum;          // exclusive prefix of this lane's group
        if (lane == 0) sex[0] = 0;
        sex[lane * 4 + 1] = base + v0;
        sex[lane * 4 + 2] = base + s01;
        sex[lane * 4 + 3] = base + s012;
        sex[lane * 4 + 4] = base + lsum;
    }
    __syncthreads();
    const int nactive = sex[N_PBLK];

    const int bid   = blockIdx.x;
    const int rbase = (bid >> 4) * R_BLK;
    if (rbase >= nactive) return;      // block-uniform exit (single barrier above)

    const int chunk = bid & (N_CHUNKS - 1);
    const int c0    = chunk * C_CHUNK;

    const int w    = tid >> 6;          // 0..3
    const int lrow = lane & 15;
    const int kg   = lane >> 4;         // 0..3
    const int s0   = rbase + w * 16;    // this wave's first row-slot

    // slot -> original row (binary search over exclusive prefix)
    auto slot2row = [&](int s) {
        int lo = 0, hi = N_PBLK;
#pragma unroll
        for (int step = 0; step < 8; ++step) {
            const int mid = (lo + hi) >> 1;
            if (sex[mid] <= s) lo = mid; else hi = mid;
        }
        return raw[lo * 32 + (s - sex[lo])];
    };

    __shared__ bf16x8 bt[2][1024];          // 32 KB, double-buffered fragment-ordered B tile
    __shared__ int    lab_s[C_CHUNK];       // 2 KB
    __shared__ float  iou_s[C_CHUNK];       // 2 KB

    // stage column metadata for this chunk (2 per thread)
#pragma unroll
    for (int i = tid; i < C_CHUNK; i += 256) {
        lab_s[i] = labels[c0 + i];
        iou_s[i] = ious[c0 + i];
    }

    // A fragments: one 16-row tile (gathered) x 256 k in registers (32 VGPR)
    bf16x8 av[8];
    {
        const int rowA = slot2row(min(s0 + lrow, nactive - 1));
        const ushort* pa = fhi + (size_t)rowA * DIM + kg * 8;
#pragma unroll
        for (int t = 0; t < 8; ++t) av[t] = *reinterpret_cast<const bf16x8*>(pa + t * 32);
    }

    // row metadata for the 4 row-slots this lane covers (C/D: col=lane&15, row=kg*4+r)
    int rowm[4]; int labi[4]; float ioui[4]; int livem = 0;
#pragma unroll
    for (int m = 0; m < 4; ++m) {
        const int slot = s0 + kg * 4 + m;
        const bool lv = slot < nactive;
        livem |= lv ? (1 << m) : 0;
        const int gi = slot2row(min(slot, nactive - 1));
        rowm[m] = gi;
        labi[m] = lv ? labels[gi] : -2;   // -2: matches no column label
        ioui[m] = ious[gi];
    }

    float ps[4] = {0.f,0.f,0.f,0.f}, as_[4] = {0.f,0.f,0.f,0.f};

    // staging in fragment order: LDS chunk L <- global fragment (half,t,lr,kg2)
    const char* fhib = (const char*)fhi;
    char* btb = (char*)&bt[0][0];
    auto stage = [&](int buf, int it) {
        const int jc = c0 + it * TILE_C;
#pragma unroll
        for (int iss = 0; iss < 4; ++iss) {
            const int L    = iss * 256 + tid;      // 0..1023
            const int half = L >> 9;
            const int rem  = L & 511;
            const int t    = rem >> 6;
            const int lr   = (rem >> 2) & 15;
            const int kg2  = rem & 3;
            const char* src = fhib + (((size_t)(jc + half * 16 + lr)) << 9) + (kg2 * 16 + t * 64);
            char* dst = btb + buf * 16384 + iss * 4096 + tid * 16;
            gload_lds16(src, dst);
        }
    };

    stage(0, 0);
    __syncthreads();    // prologue: metadata ds_writes + tile0 all resident

    const float C1 = 14.42695041f;   // 10*log2(e): e = exp2(acc*C1 - C1) == exp(sim-10)
    int cur = 0;
    for (int it = 0; it < N_ITERS; ++it) {
        if (it + 1 < N_ITERS) {
            stage(cur ^ 1, it + 1);                       // 4 loads stay in flight across compute
            asm volatile("s_waitcnt vmcnt(4)" ::: "memory");  // drain tile `it` only
        } else {
            asm volatile("s_waitcnt vmcnt(0)" ::: "memory");  // last tile: full drain
        }
        __builtin_amdgcn_s_barrier();
        __builtin_amdgcn_sched_barrier(0);   // pin ds_reads below the barrier

        const int jcl = it * TILE_C;
        const int colg0 = c0 + jcl + lrow;
        const int colg1 = colg0 + 16;
        const int labj0 = lab_s[jcl + lrow];
        const int labj1 = lab_s[jcl + 16 + lrow];
        const float iouj0 = iou_s[jcl + lrow];
        const float iouj1 = iou_s[jcl + 16 + lrow];

        f32x4 acc0 = {0.f,0.f,0.f,0.f}, acc1 = {0.f,0.f,0.f,0.f};
        const char* lbase = btb + cur * 16384 + ((lrow * 4 + kg) << 4);
#pragma unroll
        for (int t = 0; t < 8; ++t) {
            bf16x8 b0 = *reinterpret_cast<const bf16x8*>(lbase + t * 1024);
            bf16x8 b1 = *reinterpret_cast<const bf16x8*>(lbase + 8192 + t * 1024);
            acc0 = __builtin_amdgcn_mfma_f32_16x16x32_bf16(av[t], b0, acc0, 0, 0, 0);
            acc1 = __builtin_amdgcn_mfma_f32_16x16x32_bf16(av[t], b1, acc1, 0, 0, 0);
        }

        // epilogue (active rows: hi_i true, ng_i false, fg_i true):
        //   pos = same && iouj>0.5 && |d|<0.2 && fgj && i!=j
        //   allm = (fgj && i!=j) && (ioum || !same)
#pragma unroll
        for (int half = 0; half < 2; ++half) {
            const int colg = half ? colg1 : colg0;
            const int labj = half ? labj1 : labj0;
            const float iouj = half ? iouj1 : iouj0;
            const f32x4 acc = half ? acc1 : acc0;
            const bool fgj = labj >= 0;
            const bool hij = iouj > 0.5f;
#pragma unroll
            for (int m = 0; m < 4; ++m) {
                const bool same = (labi[m] == labj);
                const bool ioum = hij && (fabsf(iouj - ioui[m]) < 0.2f);
                const bool pf   = fgj && (rowm[m] != colg);
                const bool pos  = same && ioum && pf;
                const bool allm = pf && (ioum || !same);
                const float e = allm ? exp2f(fmaf(acc[m], C1, -C1)) : 0.0f;
                as_[m] += e;
                ps[m]  += pos ? e : 0.0f;
            }
        }
        __builtin_amdgcn_sched_barrier(0);
        __builtin_amdgcn_s_barrier();    // reads of buf `cur` done before it+2 overwrites it
        cur ^= 1;
    }

    // reduce over the 16 lanes (lrow) holding col-slices of the same rows
#pragma unroll
    for (int off = 1; off < 16; off <<= 1) {
#pragma unroll
        for (int m = 0; m < 4; ++m) {
            ps[m]  += __shfl_xor(ps[m], off);
            as_[m] += __shfl_xor(as_[m], off);
        }
    }

    if (lrow == 0) {
#pragma unroll
        for (int m = 0; m < 4; ++m) {
            if ((livem >> m) & 1) {
                const int idx = chunk * N_ROWS + rowm[m];
                ps_part[idx] = ps[m];
                as_part[idx] = as_[m];
            }
        }
    }
}

// ---------------- Kernel C: combine chunk partials -> per-row loss -> mean (fused) ----------------
__global__ __launch_bounds__(256) void combine_kernel(const float* __restrict__ ps_part,
                                                      const float* __restrict__ as_part,
                                                      const float* __restrict__ ious,
                                                      const int* __restrict__ labels,
                                                      float* __restrict__ partT,
                                                      float* __restrict__ partC,
                                                      int* __restrict__ done,
                                                      float* __restrict__ out) {
    const int tid = threadIdx.x;
    const int row = blockIdx.x * 256 + tid;
    const bool act = (labels[row] >= 0) && (ious[row] > 0.5f);
    float loss = 0.f, vld = 0.f;
    if (act) {
        float P = 0.f, A = 0.f;
#pragma unroll
        for (int c = 0; c < N_CHUNKS; ++c) {
            P += ps_part[c * N_ROWS + row];
            A += as_part[c * N_ROWS + row];
        }
        const float psc = fminf(fmaxf(P, 1e-6f), 1e6f);
        const float asc = fminf(fmaxf(A, 1e-6f), 1e6f);
        const bool valid = (P > 0.0f) && (A > P);
        loss = valid ? fminf(__logf(asc) - __logf(psc), 10.0f) : 0.0f;
        vld  = valid ? 1.0f : 0.0f;
    }
    float tl = loss, tc = vld;
#pragma unroll
    for (int off = 32; off; off >>= 1) { tl += __shfl_down(tl, off); tc += __shfl_down(tc, off); }
    __shared__ float sl[4], sc4[4];
    const int wid = tid >> 6;
    if ((tid & 63) == 0) { sl[wid] = tl; sc4[wid] = tc; }
    __syncthreads();
    if (tid == 0) {
        partT[blockIdx.x] = sl[0] + sl[1] + sl[2] + sl[3];
        partC[blockIdx.x] = sc4[0] + sc4[1] + sc4[2] + sc4[3];
        __threadfence();
        const int prev = atomicAdd(done, 1);
        if (prev == (int)gridDim.x - 1) {      // last block finalizes (fixed order: deterministic)
            __threadfence();
            float T = 0.f, C = 0.f;
#pragma unroll
            for (int b = 0; b < N_ROWS / 256; ++b) { T += partT[b]; C += partC[b]; }
            out[0] = (C > 0.f) ? (T / C) : 0.0f;
        }
    }
}

extern "C" void kernel_launch(void* const* d_in, const int* in_sizes, int n_in,
                              void* d_out, int out_size, void* d_ws, size_t ws_size,
                              hipStream_t stream) {
    const float* feat   = (const float*)d_in[0];
    const float* ious   = (const float*)d_in[1];
    const int*   labels = (const int*)d_in[2];
    float* out = (float*)d_out;

    ushort* fhi = (ushort*)d_ws;                                     // 4 MB
    float*  ps_part = (float*)(fhi + (size_t)N_ROWS * DIM);          // 512 KB
    float*  as_part = ps_part + (size_t)N_CHUNKS * N_ROWS;           // 512 KB
    int*    raw  = (int*)(as_part + (size_t)N_CHUNKS * N_ROWS);      // 32 KB
    int*    cnt  = raw + N_ROWS;                                     // 1 KB
    int*    done = cnt + N_PBLK;                                     // 4 B
    float*  partT = (float*)(done + 1);                              // 32 floats
    float*  partC = partT + (N_ROWS / 256);                          // 32 floats

    prep_kernel<<<N_PBLK, 256, 0, stream>>>(feat, ious, labels, fhi, raw, cnt, done);
    main_kernel<<<(N_ROWS / R_BLK) * N_CHUNKS, 256, 0, stream>>>(fhi, ious, labels,
                                                                 raw, cnt, ps_part, as_part);
    combine_kernel<<<N_ROWS / 256, 256, 0, stream>>>(ps_part, as_part, ious, labels,
                                                     partT, partC, done, out);
}

// Round 26
// 49.900 us; speedup vs baseline: 2.0273x; 1.0265x over previous
//
#include <hip/hip_runtime.h>
#include <hip/hip_bf16.h>

#define N_ROWS 8192
#define DIM 256
#define R_BLK 64           // row-slots per block (4 waves x 16)
#define C_CHUNK 512        // cols per block
#define TILE_C 32          // cols per LDS tile
#define N_CHUNKS 16
#define N_ITERS (C_CHUNK / TILE_C)   // 16
#define N_PBLK 512         // prep blocks (16 rows each)

typedef __attribute__((ext_vector_type(4))) float f32x4;
typedef __attribute__((ext_vector_type(8))) short bf16x8;

__device__ __forceinline__ void gload_lds16(const void* g, void* l) {
    using gv = const __attribute__((address_space(1))) void*;
    using sv = __attribute__((address_space(3))) void*;
    __builtin_amdgcn_global_load_lds((gv)g, (sv)l, 16, 0, 0);
}

__device__ __forceinline__ ushort f2bf(float v) {
    __hip_bfloat16 h = __float2bfloat16(v);
    return *reinterpret_cast<ushort*>(&h);
}

// ---------------- Kernel A: normalize rows -> bf16 + per-block local compaction ----------------
// 512 blocks x 16 rows (2 blocks/CU, 4 serial row-groups instead of 8).
// NO atomics: block b writes cnt[b] + locally-compacted raw[b*16..]. Deterministic.
__global__ __launch_bounds__(256) void prep_kernel(const float* __restrict__ feat,
                                                   const float* __restrict__ ious,
                                                   const int* __restrict__ labels,
                                                   ushort* __restrict__ fhi,
                                                   int* __restrict__ raw,
                                                   int* __restrict__ cnt,
                                                   int* __restrict__ done) {
    if (blockIdx.x == 0 && threadIdx.x == 0) done[0] = 0;
    const int wid  = threadIdx.x >> 6;
    const int lane = threadIdx.x & 63;
#pragma unroll
    for (int r4 = 0; r4 < 4; ++r4) {
        const int row = blockIdx.x * 16 + r4 * 4 + wid;
        const float4 x = reinterpret_cast<const float4*>(feat + (size_t)row * DIM)[lane];
        float ss = x.x * x.x + x.y * x.y + x.z * x.z + x.w * x.w;
#pragma unroll
        for (int off = 32; off; off >>= 1) ss += __shfl_xor(ss, off);
        const float inv = 1.0f / fmaxf(sqrtf(ss), 1e-12f);
        ushort4 h;
        h.x = f2bf(x.x * inv); h.y = f2bf(x.y * inv);
        h.z = f2bf(x.z * inv); h.w = f2bf(x.w * inv);
        reinterpret_cast<ushort4*>(fhi + (size_t)row * DIM)[lane] = h;
    }
    if (threadIdx.x < 64) {            // wave 0: local compaction of this block's 16 rows
        const int row = blockIdx.x * 16 + (lane & 15);
        const bool act = (lane < 16) && (labels[row] >= 0) && (ious[row] > 0.5f);
        const unsigned long long mb = __ballot(act);
        const int off = __popcll(mb & ((1ull << lane) - 1ull));
        if (act) raw[blockIdx.x * 16 + off] = row;
        if (lane == 0) cnt[blockIdx.x] = __popcll(mb);
    }
}

// ---------------- Kernel B: fused tiled sim + mask + fixed-max softmax partials ----------------
// grid = 2048: chunk = bid&15 (512 cols), rowblk = bid>>4 (64 active-row slots, 16/wave).
// Prologue: wave-0 shuffle scan of cnt[512] (8/lane) -> sex[] prefix; dead blocks exit fast.
// B tile in MFMA-FRAGMENT ORDER. CANONICAL SINGLE-BARRIER 2-phase loop:
//   stage(next) -> compute(cur) -> vmcnt(0) [loads landed during compute] -> s_barrier.
__global__ __launch_bounds__(256, 4) void main_kernel(const ushort* __restrict__ fhi,
                                                      const float* __restrict__ ious,
                                                      const int* __restrict__ labels,
                                                      const int* __restrict__ raw,
                                                      const int* __restrict__ cnt,
                                                      float* __restrict__ ps_part,
                                                      float* __restrict__ as_part) {
    const int tid  = threadIdx.x;
    const int lane = tid & 63;

    __shared__ int sex[N_PBLK + 1];  // exclusive prefix of cnt
    if (tid < 64) {                  // wave-0 scan: 8 cnt values per lane
        int v[8], p[8];
        int lsum = 0;
#pragma unroll
        for (int k = 0; k < 8; ++k) { v[k] = cnt[lane * 8 + k]; p[k] = lsum; lsum += v[k]; }
        int inc = lsum;
#pragma unroll
        for (int off = 1; off < 64; off <<= 1) {
            const int t = __shfl_up(inc, off);
            if (lane >= off) inc += t;
        }
        const int base = inc - lsum;          // exclusive prefix of this lane's group
        if (lane == 0) sex[0] = 0;
#pragma unroll
        for (int k = 0; k < 8; ++k) sex[lane * 8 + k + 1] = base + p[k] + v[k];
    }
    __syncthreads();
    const int nactive = sex[N_PBLK];

    const int bid   = blockIdx.x;
    const int rbase = (bid >> 4) * R_BLK;
    if (rbase >= nactive) return;      // block-uniform exit (single barrier above)

    const int chunk = bid & (N_CHUNKS - 1);
    const int c0    = chunk * C_CHUNK;

    const int w    = tid >> 6;          // 0..3
    const int lrow = lane & 15;
    const int kg   = lane >> 4;         // 0..3
    const int s0   = rbase + w * 16;    // this wave's first row-slot

    // slot -> original row (binary search over exclusive prefix, 9 steps for 512)
    auto slot2row = [&](int s) {
        int lo = 0, hi = N_PBLK;
#pragma unroll
        for (int step = 0; step < 9; ++step) {
            const int mid = (lo + hi) >> 1;
            if (sex[mid] <= s) lo = mid; else hi = mid;
        }
        return raw[lo * 16 + (s - sex[lo])];
    };

    __shared__ bf16x8 bt[2][1024];          // 32 KB, double-buffered fragment-ordered B tile
    __shared__ int    lab_s[C_CHUNK];       // 2 KB
    __shared__ float  iou_s[C_CHUNK];       // 2 KB

    // stage column metadata for this chunk (2 per thread)
#pragma unroll
    for (int i = tid; i < C_CHUNK; i += 256) {
        lab_s[i] = labels[c0 + i];
        iou_s[i] = ious[c0 + i];
    }

    // A fragments: one 16-row tile (gathered) x 256 k in registers (32 VGPR)
    bf16x8 av[8];
    {
        const int rowA = slot2row(min(s0 + lrow, nactive - 1));
        const ushort* pa = fhi + (size_t)rowA * DIM + kg * 8;
#pragma unroll
        for (int t = 0; t < 8; ++t) av[t] = *reinterpret_cast<const bf16x8*>(pa + t * 32);
    }

    // row metadata for the 4 row-slots this lane covers (C/D: col=lane&15, row=kg*4+r)
    int rowm[4]; int labi[4]; float ioui[4]; int livem = 0;
#pragma unroll
    for (int m = 0; m < 4; ++m) {
        const int slot = s0 + kg * 4 + m;
        const bool lv = slot < nactive;
        livem |= lv ? (1 << m) : 0;
        const int gi = slot2row(min(slot, nactive - 1));
        rowm[m] = gi;
        labi[m] = lv ? labels[gi] : -2;   // -2: matches no column label
        ioui[m] = ious[gi];
    }

    float ps[4] = {0.f,0.f,0.f,0.f}, as_[4] = {0.f,0.f,0.f,0.f};

    // staging in fragment order: LDS chunk L <- global fragment (half,t,lr,kg2)
    const char* fhib = (const char*)fhi;
    char* btb = (char*)&bt[0][0];
    auto stage = [&](int buf, int it) {
        const int jc = c0 + it * TILE_C;
#pragma unroll
        for (int iss = 0; iss < 4; ++iss) {
            const int L    = iss * 256 + tid;      // 0..1023
            const int half = L >> 9;
            const int rem  = L & 511;
            const int t    = rem >> 6;
            const int lr   = (rem >> 2) & 15;
            const int kg2  = rem & 3;
            const char* src = fhib + (((size_t)(jc + half * 16 + lr)) << 9) + (kg2 * 16 + t * 64);
            char* dst = btb + buf * 16384 + iss * 4096 + tid * 16;
            gload_lds16(src, dst);
        }
    };

    stage(0, 0);
    __syncthreads();    // prologue: metadata ds_writes + tile0 all resident

    const float C1 = 14.42695041f;   // 10*log2(e): e = exp2(acc*C1 - C1) == exp(sim-10)
    int cur = 0;
    for (int it = 0; it < N_ITERS; ++it) {
        if (it + 1 < N_ITERS) stage(cur ^ 1, it + 1);   // loads land during compute below

        const int jcl = it * TILE_C;
        const int colg0 = c0 + jcl + lrow;
        const int colg1 = colg0 + 16;
        const int labj0 = lab_s[jcl + lrow];
        const int labj1 = lab_s[jcl + 16 + lrow];
        const float iouj0 = iou_s[jcl + lrow];
        const float iouj1 = iou_s[jcl + 16 + lrow];

        f32x4 acc0 = {0.f,0.f,0.f,0.f}, acc1 = {0.f,0.f,0.f,0.f};
        const char* lbase = btb + cur * 16384 + ((lrow * 4 + kg) << 4);
#pragma unroll
        for (int t = 0; t < 8; ++t) {
            bf16x8 b0 = *reinterpret_cast<const bf16x8*>(lbase + t * 1024);
            bf16x8 b1 = *reinterpret_cast<const bf16x8*>(lbase + 8192 + t * 1024);
            acc0 = __builtin_amdgcn_mfma_f32_16x16x32_bf16(av[t], b0, acc0, 0, 0, 0);
            acc1 = __builtin_amdgcn_mfma_f32_16x16x32_bf16(av[t], b1, acc1, 0, 0, 0);
        }

        // epilogue (active rows: hi_i true, ng_i false, fg_i true):
        //   pos = same && iouj>0.5 && |d|<0.2 && fgj && i!=j
        //   allm = (fgj && i!=j) && (ioum || !same)
#pragma unroll
        for (int half = 0; half < 2; ++half) {
            const int colg = half ? colg1 : colg0;
            const int labj = half ? labj1 : labj0;
            const float iouj = half ? iouj1 : iouj0;
            const f32x4 acc = half ? acc1 : acc0;
            const bool fgj = labj >= 0;
            const bool hij = iouj > 0.5f;
#pragma unroll
            for (int m = 0; m < 4; ++m) {
                const bool same = (labi[m] == labj);
                const bool ioum = hij && (fabsf(iouj - ioui[m]) < 0.2f);
                const bool pf   = fgj && (rowm[m] != colg);
                const bool pos  = same && ioum && pf;
                const bool allm = pf && (ioum || !same);
                const float e = allm ? exp2f(fmaf(acc[m], C1, -C1)) : 0.0f;
                as_[m] += e;
                ps[m]  += pos ? e : 0.0f;
            }
        }
        // single barrier per iter: my stage loads completed during compute -> vmcnt(0) ~free;
        // barrier then guarantees (a) all waves' tile-(it+1) writes landed, (b) all reads of
        // buf `cur` done before iter it+1 stages tile it+2 into it.
        asm volatile("s_waitcnt vmcnt(0)" ::: "memory");
        __builtin_amdgcn_s_barrier();
        __builtin_amdgcn_sched_barrier(0);
        cur ^= 1;
    }

    // reduce over the 16 lanes (lrow) holding col-slices of the same rows
#pragma unroll
    for (int off = 1; off < 16; off <<= 1) {
#pragma unroll
        for (int m = 0; m < 4; ++m) {
            ps[m]  += __shfl_xor(ps[m], off);
            as_[m] += __shfl_xor(as_[m], off);
        }
    }

    if (lrow == 0) {
#pragma unroll
        for (int m = 0; m < 4; ++m) {
            if ((livem >> m) & 1) {
                const int idx = chunk * N_ROWS + rowm[m];
                ps_part[idx] = ps[m];
                as_part[idx] = as_[m];
            }
        }
    }
}

// ---------------- Kernel C: combine chunk partials -> per-row loss -> mean (fused) ----------------
__global__ __launch_bounds__(256) void combine_kernel(const float* __restrict__ ps_part,
                                                      const float* __restrict__ as_part,
                                                      const float* __restrict__ ious,
                                                      const int* __restrict__ labels,
                                                      float* __restrict__ partT,
                                                      float* __restrict__ partC,
                                                      int* __restrict__ done,
                                                      float* __restrict__ out) {
    const int tid = threadIdx.x;
    const int row = blockIdx.x * 256 + tid;
    const bool act = (labels[row] >= 0) && (ious[row] > 0.5f);
    float loss = 0.f, vld = 0.f;
    if (act) {
        float P = 0.f, A = 0.f;
#pragma unroll
        for (int c = 0; c < N_CHUNKS; ++c) {
            P += ps_part[c * N_ROWS + row];
            A += as_part[c * N_ROWS + row];
        }
        const float psc = fminf(fmaxf(P, 1e-6f), 1e6f);
        const float asc = fminf(fmaxf(A, 1e-6f), 1e6f);
        const bool valid = (P > 0.0f) && (A > P);
        loss = valid ? fminf(__logf(asc) - __logf(psc), 10.0f) : 0.0f;
        vld  = valid ? 1.0f : 0.0f;
    }
    float tl = loss, tc = vld;
#pragma unroll
    for (int off = 32; off; off >>= 1) { tl += __shfl_down(tl, off); tc += __shfl_down(tc, off); }
    __shared__ float sl[4], sc4[4];
    const int wid = tid >> 6;
    if ((tid & 63) == 0) { sl[wid] = tl; sc4[wid] = tc; }
    __syncthreads();
    if (tid == 0) {
        partT[blockIdx.x] = sl[0] + sl[1] + sl[2] + sl[3];
        partC[blockIdx.x] = sc4[0] + sc4[1] + sc4[2] + sc4[3];
        __threadfence();
        const int prev = atomicAdd(done, 1);
        if (prev == (int)gridDim.x - 1) {      // last block finalizes (fixed order: deterministic)
            __threadfence();
            float T = 0.f, C = 0.f;
#pragma unroll
            for (int b = 0; b < N_ROWS / 256; ++b) { T += partT[b]; C += partC[b]; }
            out[0] = (C > 0.f) ? (T / C) : 0.0f;
        }
    }
}

extern "C" void kernel_launch(void* const* d_in, const int* in_sizes, int n_in,
                              void* d_out, int out_size, void* d_ws, size_t ws_size,
                              hipStream_t stream) {
    const float* feat   = (const float*)d_in[0];
    const float* ious   = (const float*)d_in[1];
    const int*   labels = (const int*)d_in[2];
    float* out = (float*)d_out;

    ushort* fhi = (ushort*)d_ws;                                     // 4 MB
    float*  ps_part = (float*)(fhi + (size_t)N_ROWS * DIM);          // 512 KB
    float*  as_part = ps_part + (size_t)N_CHUNKS * N_ROWS;           // 512 KB
    int*    raw  = (int*)(as_part + (size_t)N_CHUNKS * N_ROWS);      // 32 KB
    int*    cnt  = raw + N_ROWS;                                     // 2 KB
    int*    done = cnt + N_PBLK;                                     // 4 B
    float*  partT = (float*)(done + 1);                              // 32 floats
    float*  partC = partT + (N_ROWS / 256);                          // 32 floats

    prep_kernel<<<N_PBLK, 256, 0, stream>>>(feat, ious, labels, fhi, raw, cnt, done);
    main_kernel<<<(N_ROWS / R_BLK) * N_CHUNKS, 256, 0, stream>>>(fhi, ious, labels,
                                                                 raw, cnt, ps_part, as_part);
    combine_kernel<<<N_ROWS / 256, 256, 0, stream>>>(ps_part, as_part, ious, labels,
                                                     partT, partC, done, out);
}